// Round 10
// baseline (448.369 us; speedup 1.0000x reference)
//
#include <hip/hip_runtime.h>
#include <hip/hip_bf16.h>

// GeniePath forward: lin1 -> [GAT(edge softmax) + LSTM] x2 -> lin2
// R9: k_gat reverted to R7 lane-owns-edge (measured best, 71us; R8's
//     4-lane-coop regressed: instruction count dominates, not lines).
//     NEW: weight-staging prologue de-conflicted (j=i>>6,row=i&63 ->
//     consecutive threads hit consecutive addresses; the constant 9M
//     SQ_LDS_BANK_CONFLICT was 16-way conflicts in this prologue, not
//     the edge loop). Parallel scan (R8's one win) kept.

#define NN 100000
#define NE 3200000
#define IND 256
#define HD 16
#define OD 64
#define NL 2

#define NBK 512        // P0/P1 block count
#define CHUNK 6250     // NE / NBK, exact
#define NBUCKET 256    // coarse buckets (dst >> 9); 196 used
#define BSHIFT 9
#define NBUSED ((NN + 511) >> 9)  // 196

__device__ __forceinline__ float fsig(float x) {
  return 1.0f / (1.0f + __expf(-x));
}
// stable tanh: works for any magnitude (expf overflow -> +inf -> 2/inf = 0)
__device__ __forceinline__ float ftanh(float x) {
  float a = fabsf(x);
  float t = 1.0f - 2.0f / (__expf(2.0f * a) + 1.0f);
  return x < 0.0f ? -t : t;
}
__device__ __forceinline__ float leaky(float e) {
  return e > 0.0f ? e : 0.2f * e;
}

__device__ __forceinline__ int block_excl_scan(int v, int* lds) {
  const int lane = threadIdx.x & 63;
  const int w = threadIdx.x >> 6;
  const int nw = blockDim.x >> 6;
  int inc = v;
#pragma unroll
  for (int d = 1; d < 64; d <<= 1) {
    int u = __shfl_up(inc, d);
    if (lane >= d) inc += u;
  }
  if (lane == 63) lds[w] = inc;
  __syncthreads();
  int wbase = 0;
  for (int i = 0; i < nw; ++i) {
    int s = lds[i];
    if (i < w) wbase += s;
  }
  return wbase + inc - v;
}

// ---------------- lin1: y[N,16] = x[N,256] @ w[16,256]^T + b ----------------
__global__ __launch_bounds__(256) void k_lin1(const float* __restrict__ x,
                                              const float* __restrict__ w,
                                              const float* __restrict__ bias,
                                              float* __restrict__ y) {
  const int lane = threadIdx.x & 63;
  const int wid = (blockIdx.x * (blockDim.x >> 6)) + (threadIdx.x >> 6);
  const int nw = (gridDim.x * blockDim.x) >> 6;
  float4 wr[HD];
#pragma unroll
  for (int k = 0; k < HD; ++k)
    wr[k] = *reinterpret_cast<const float4*>(&w[k * IND + lane * 4]);
  // lane l (low 16) owns output k = bitrev4(l)
  const int krev = ((lane & 1) << 3) | ((lane & 2) << 1) | ((lane & 4) >> 1) | ((lane & 8) >> 3);
  const float bl = bias[krev];
  const int b0 = lane & 1, b1 = lane & 2, b2 = lane & 4, b3 = lane & 8;

  for (int n = wid; n < NN; n += nw) {
    float4 xv = *reinterpret_cast<const float4*>(&x[n * IND + lane * 4]);
    float acc[HD];
#pragma unroll
    for (int k = 0; k < HD; ++k)
      acc[k] = xv.x * wr[k].x + xv.y * wr[k].y + xv.z * wr[k].z + xv.w * wr[k].w;
    float v8[8];
#pragma unroll
    for (int j = 0; j < 8; ++j) {
      float send = b0 ? acc[j] : acc[j + 8];
      float recv = __shfl_xor(send, 1);
      v8[j] = (b0 ? acc[j + 8] : acc[j]) + recv;
    }
    float v4[4];
#pragma unroll
    for (int j = 0; j < 4; ++j) {
      float send = b1 ? v8[j] : v8[j + 4];
      float recv = __shfl_xor(send, 2);
      v4[j] = (b1 ? v8[j + 4] : v8[j]) + recv;
    }
    float v2[2];
#pragma unroll
    for (int j = 0; j < 2; ++j) {
      float send = b2 ? v4[j] : v4[j + 2];
      float recv = __shfl_xor(send, 4);
      v2[j] = (b2 ? v4[j + 2] : v4[j]) + recv;
    }
    float send = b3 ? v2[0] : v2[1];
    float recv = __shfl_xor(send, 8);
    float v1 = (b3 ? v2[1] : v2[0]) + recv;
    v1 += __shfl_xor(v1, 16);
    v1 += __shfl_xor(v1, 32);
    if (lane < HD) y[n * HD + krev] = v1 + bl;
  }
}

// ---------------- per-node GAT prologue: feat, el, er ----------------
__global__ __launch_bounds__(256) void k_node(const float* __restrict__ xin,
                                              const float* __restrict__ fc,
                                              const float* __restrict__ al,
                                              const float* __restrict__ ar,
                                              float* __restrict__ feat,
                                              float* __restrict__ el,
                                              float* __restrict__ er) {
  int n = blockIdx.x * blockDim.x + threadIdx.x;
  if (n >= NN) return;
  const float4* xp = reinterpret_cast<const float4*>(&xin[n * HD]);
  float xr[HD];
#pragma unroll
  for (int j = 0; j < 4; ++j) {
    float4 v = xp[j];
    xr[4 * j] = v.x; xr[4 * j + 1] = v.y; xr[4 * j + 2] = v.z; xr[4 * j + 3] = v.w;
  }
  float fr[HD];
  float e_l = 0.0f, e_r = 0.0f;
#pragma unroll
  for (int k = 0; k < HD; ++k) {
    float acc = 0.0f;
#pragma unroll
    for (int j = 0; j < HD; ++j) acc += xr[j] * fc[k * HD + j];
    fr[k] = acc;
    e_l += acc * al[k];
    e_r += acc * ar[k];
  }
  float4* fp = reinterpret_cast<float4*>(&feat[n * HD]);
  fp[0] = make_float4(fr[0], fr[1], fr[2], fr[3]);
  fp[1] = make_float4(fr[4], fr[5], fr[6], fr[7]);
  fp[2] = make_float4(fr[8], fr[9], fr[10], fr[11]);
  fp[3] = make_float4(fr[12], fr[13], fr[14], fr[15]);
  el[n] = e_l;
  er[n] = e_r;
}

// ---------------- build P0: per-block coarse histogram (no atomics) --------
__global__ __launch_bounds__(256) void k_p0(const int* __restrict__ dst,
                                            int* __restrict__ part) {
  __shared__ int hist[NBUCKET];
  for (int i = threadIdx.x; i < NBUCKET; i += 256) hist[i] = 0;
  __syncthreads();
  const int base = blockIdx.x * CHUNK;
  for (int i = threadIdx.x; i < CHUNK; i += 256)
    atomicAdd(&hist[dst[base + i] >> BSHIFT], 1);  // LDS atomic, cheap
  __syncthreads();
  for (int i = threadIdx.x; i < NBUCKET; i += 256)
    part[blockIdx.x * NBUCKET + i] = hist[i];
}

// ---------------- build scan (parallel): per-bucket block scan -------------
// one block per bucket b: scan part[0..511][b] in place, write totals[b]
__global__ __launch_bounds__(256) void k_scan1(int* __restrict__ part,
                                               int* __restrict__ totals) {
  __shared__ int lds[4];
  const int b = blockIdx.x;
  const int t = threadIdx.x;
  int v0 = part[(2 * t) * NBUCKET + b];
  int v1 = part[(2 * t + 1) * NBUCKET + b];
  int sum = v0 + v1;
  int ex = block_excl_scan(sum, lds);
  part[(2 * t) * NBUCKET + b] = ex;
  part[(2 * t + 1) * NBUCKET + b] = ex + v0;
  if (t == 255) totals[b] = ex + sum;
}

// exclusive scan of 256 bucket totals -> segbase
__global__ __launch_bounds__(256) void k_scan2(const int* __restrict__ totals,
                                               int* __restrict__ segbase) {
  __shared__ int lds[4];
  const int t = threadIdx.x;
  int v = totals[t];
  int ex = block_excl_scan(v, lds);
  segbase[t] = ex;
  if (t == NBUCKET - 1) segbase[NBUCKET] = ex + v;
}

// ---------------- build P1: bucket-grouped coalesced scatter ---------------
__global__ __launch_bounds__(256) void k_p1(const int* __restrict__ src,
                                            const int* __restrict__ dst,
                                            const int* __restrict__ part,
                                            const int* __restrict__ segbase,
                                            int* __restrict__ binned) {
  __shared__ int hist[NBUCKET];
  __shared__ int sc[NBUCKET];      // exclusive scan of hist (LDS layout)
  __shared__ int gb[NBUCKET];      // global base for this block's run per bucket
  __shared__ int cur[NBUCKET];
  __shared__ int stage[CHUNK];     // packed (src<<9 | dst&511), bucket-grouped
  __shared__ unsigned char bkt[CHUNK];
  __shared__ int lds4[4];
  for (int i = threadIdx.x; i < NBUCKET; i += 256) hist[i] = 0;
  __syncthreads();
  const int base = blockIdx.x * CHUNK;
  for (int i = threadIdx.x; i < CHUNK; i += 256)
    atomicAdd(&hist[dst[base + i] >> BSHIFT], 1);
  __syncthreads();
  {
    int v = hist[threadIdx.x];
    int ex = block_excl_scan(v, lds4);
    sc[threadIdx.x] = ex;
    cur[threadIdx.x] = 0;
    gb[threadIdx.x] = segbase[threadIdx.x] + part[blockIdx.x * NBUCKET + threadIdx.x];
  }
  __syncthreads();
  // stage bucket-grouped into LDS
  for (int i = threadIdx.x; i < CHUNK; i += 256) {
    int d = dst[base + i];
    int s = src[base + i];
    int b = d >> BSHIFT;
    int l = atomicAdd(&cur[b], 1);
    int slot = sc[b] + l;
    stage[slot] = (s << BSHIFT) | (d & ((1 << BSHIFT) - 1));
    bkt[slot] = (unsigned char)b;
  }
  __syncthreads();
  // stream out: consecutive slots -> same bucket mostly -> coalesced
  for (int i = threadIdx.x; i < CHUNK; i += 256) {
    int b = bkt[i];
    binned[gb[b] + (i - sc[b])] = stage[i];
  }
}

// ---------------- build P2: per-bucket fine CSR ----------------------------
__global__ __launch_bounds__(512) void k_p2(const int* __restrict__ binned,
                                            const int* __restrict__ segbase,
                                            int* __restrict__ off,
                                            int* __restrict__ csr) {
  const int b = blockIdx.x;  // 0..NBUSED-1
  const int lo = segbase[b];
  const int cnt = segbase[b + 1] - lo;
  __shared__ int hist[512], sc2[512], cur2[512];
  __shared__ int lds8[8];
  hist[threadIdx.x] = 0;
  __syncthreads();
  for (int i = threadIdx.x; i < cnt; i += 512)
    atomicAdd(&hist[binned[lo + i] & 511], 1);
  __syncthreads();
  int v = hist[threadIdx.x];
  int ex = block_excl_scan(v, lds8);
  sc2[threadIdx.x] = ex;
  cur2[threadIdx.x] = 0;
  int node = (b << BSHIFT) + threadIdx.x;
  if (node < NN) off[node] = lo + ex;
  if (b == 0 && threadIdx.x == 0) off[NN] = NE;
  __syncthreads();
  for (int i = threadIdx.x; i < cnt; i += 512) {
    int w = binned[lo + i];
    int ld = w & 511;
    int l = atomicAdd(&cur2[ld], 1);          // LDS atomic
    csr[lo + sc2[ld] + l] = w >> BSHIFT;      // write within L2-resident window
  }
}

// ---------------- fused GAT aggregate + LSTM cell (+ lin2 on last layer) ----
// block = 256 thr = 4 waves; wave = 4 nodes x 16 lanes.
// Edge loop (R7): lane q owns edge t0+q end-to-end (loads its own 64B feat
// row, weights by its own ex). acc[] indexed by bitrev4(dim) so the
// value-halving butterfly lands dim p on lane p. Zero DS in the loop.
__global__ __launch_bounds__(256) void k_gat(const float* __restrict__ feat,
                                             const float* __restrict__ el,
                                             const float* __restrict__ er,
                                             const int* __restrict__ off,
                                             const int* __restrict__ csr_src,
                                             const float* __restrict__ gbias,
                                             const float* __restrict__ wih,
                                             const float* __restrict__ whh,
                                             const float* __restrict__ bih,
                                             const float* __restrict__ bhh,
                                             const float* __restrict__ h_in,
                                             const float* __restrict__ c_in,
                                             float* __restrict__ h_out,
                                             float* __restrict__ c_out,
                                             const float* __restrict__ w2,
                                             const float* __restrict__ b2,
                                             float* __restrict__ out,
                                             int first, int last) {
  __shared__ float s_wih[HD][64];  // [j][gate*16+p]
  __shared__ float s_whh[HD][64];
  __shared__ float s_b[64];
  __shared__ float s_gb[HD];
  __shared__ float s_w2[HD][OD];   // [j][o]
  __shared__ float s_b2[OD];
  // staging: j = i>>6, row = i&63 -> consecutive threads write consecutive
  // LDS addresses (conflict-free; the old i&15/i>>4 mapping was a 16-way
  // bank conflict = the constant 9M SQ_LDS_BANK_CONFLICT).
  for (int i = threadIdx.x; i < 64 * HD; i += blockDim.x) {
    int j = i >> 6;
    int row = i & 63;
    s_wih[j][row] = wih[row * HD + j];
    s_whh[j][row] = whh[row * HD + j];
    s_w2[j][row] = w2[row * HD + j];  // 64 rows x 16 cols, same shape
  }
  if (threadIdx.x < 64) {
    s_b[threadIdx.x] = bih[threadIdx.x] + bhh[threadIdx.x];
    s_b2[threadIdx.x] = b2[threadIdx.x];
  }
  if (threadIdx.x < HD) s_gb[threadIdx.x] = gbias[threadIdx.x];
  __syncthreads();

  const int lane = threadIdx.x & 63;
  const int p = lane & 15;
  const int lb = lane & 48;  // group base lane
  const int grp = lane >> 4;
  const int wave = threadIdx.x >> 6;
  int n = blockIdx.x * 16 + wave * 4 + grp;
  bool valid = n < NN;
  int base = 0, deg = 0;
  float ern = 0.0f;
  if (valid) {
    base = off[n];
    deg = off[n + 1] - base;
    ern = er[n];
  }
  const int b0 = lane & 1, b1 = lane & 2, b2_ = lane & 4, b3 = lane & 8;

  // softmax without max subtraction (scale-invariant; logits O(5) by
  // construction). Lane q of the group owns edges t0+q: private ex,
  // private acc[16] over its edges' feat rows. acc[bitrev4(k)] = dim k.
  float ssum = 0.0f;
  float acc[HD];
#pragma unroll
  for (int k = 0; k < HD; ++k) acc[k] = 0.0f;
  for (int t0 = 0; t0 < deg; t0 += 16) {
    int t = t0 + p;
    bool ok = t < deg;
    int tc = ok ? t : (deg - 1);        // clamped: loads always safe
    int s = csr_src[base + tc];         // coalesced 64B per group
    float ex = ok ? __expf(leaky(el[s] + ern)) : 0.0f;
    ssum += ex;
    const float4* fp4 = reinterpret_cast<const float4*>(&feat[s * HD]);
    float4 f0 = fp4[0], f1 = fp4[1], f2 = fp4[2], f3 = fp4[3];
    // dim k -> acc[bitrev4(k)]
    acc[0]  += ex * f0.x;  // k=0
    acc[8]  += ex * f0.y;  // k=1
    acc[4]  += ex * f0.z;  // k=2
    acc[12] += ex * f0.w;  // k=3
    acc[2]  += ex * f1.x;  // k=4
    acc[10] += ex * f1.y;  // k=5
    acc[6]  += ex * f1.z;  // k=6
    acc[14] += ex * f1.w;  // k=7
    acc[1]  += ex * f2.x;  // k=8
    acc[9]  += ex * f2.y;  // k=9
    acc[5]  += ex * f2.z;  // k=10
    acc[13] += ex * f2.w;  // k=11
    acc[3]  += ex * f3.x;  // k=12
    acc[11] += ex * f3.y;  // k=13
    acc[7]  += ex * f3.z;  // k=14
    acc[15] += ex * f3.w;  // k=15
  }
  // ssum: all-reduce within the 16-lane group (4 shuffles)
  ssum += __shfl_xor(ssum, 1);
  ssum += __shfl_xor(ssum, 2);
  ssum += __shfl_xor(ssum, 4);
  ssum += __shfl_xor(ssum, 8);
  // value-halving butterfly: lane l ends with acc[bitrev4(l)] = dim l total
  float v8[8];
#pragma unroll
  for (int j = 0; j < 8; ++j) {
    float send = b0 ? acc[j] : acc[j + 8];
    float recv = __shfl_xor(send, 1);
    v8[j] = (b0 ? acc[j + 8] : acc[j]) + recv;
  }
  float v4[4];
#pragma unroll
  for (int j = 0; j < 4; ++j) {
    float send = b1 ? v8[j] : v8[j + 4];
    float recv = __shfl_xor(send, 2);
    v4[j] = (b1 ? v8[j + 4] : v8[j]) + recv;
  }
  float v2[2];
#pragma unroll
  for (int j = 0; j < 2; ++j) {
    float send = b2_ ? v4[j] : v4[j + 2];
    float recv = __shfl_xor(send, 4);
    v2[j] = (b2_ ? v4[j + 2] : v4[j]) + recv;
  }
  float send1 = b3 ? v2[0] : v2[1];
  float recv1 = __shfl_xor(send1, 8);
  float a = (b3 ? v2[1] : v2[0]) + recv1;

  float inv = (deg > 0) ? 1.0f / ssum : 0.0f;
  float g_in = ftanh(a * inv + s_gb[p]);

  // LSTM cell (dim p of node n)
  float h_old = 0.0f, c_old = 0.0f;
  if (!first && valid) {
    h_old = h_in[n * HD + p];
    c_old = c_in[n * HD + p];
  }
  float g0 = 0.0f, g1 = 0.0f, g2 = 0.0f, g3 = 0.0f;
#pragma unroll
  for (int j = 0; j < HD; ++j) {
    float gj = __shfl(g_in, lb + j);
    float hj = __shfl(h_old, lb + j);
    g0 += gj * s_wih[j][p] + hj * s_whh[j][p];
    g1 += gj * s_wih[j][16 + p] + hj * s_whh[j][16 + p];
    g2 += gj * s_wih[j][32 + p] + hj * s_whh[j][32 + p];
    g3 += gj * s_wih[j][48 + p] + hj * s_whh[j][48 + p];
  }
  g0 += s_b[p]; g1 += s_b[16 + p]; g2 += s_b[32 + p]; g3 += s_b[48 + p];
  float ig = fsig(g0), fg = fsig(g1), gg = ftanh(g2), og = fsig(g3);
  float c_new = fg * c_old + ig * gg;
  float h_new = og * ftanh(c_new);

  if (valid) {
    if (!last) {
      h_out[n * HD + p] = h_new;
      c_out[n * HD + p] = c_new;
    } else {
      // fused lin2: out[n,o] = sum_j h[j] * w2[o][j] + b2[o]
      float o0 = s_b2[p], o1 = s_b2[16 + p], o2 = s_b2[32 + p], o3 = s_b2[48 + p];
#pragma unroll
      for (int j = 0; j < HD; ++j) {
        float hj = __shfl(h_new, lb + j);
        o0 += hj * s_w2[j][p];
        o1 += hj * s_w2[j][16 + p];
        o2 += hj * s_w2[j][32 + p];
        o3 += hj * s_w2[j][48 + p];
      }
      out[n * OD + p] = o0;
      out[n * OD + 16 + p] = o1;
      out[n * OD + 32 + p] = o2;
      out[n * OD + 48 + p] = o3;
    }
  }
}

extern "C" void kernel_launch(void* const* d_in, const int* in_sizes, int n_in,
                              void* d_out, int out_size, void* d_ws, size_t ws_size,
                              hipStream_t stream) {
  const float* x = (const float*)d_in[0];
  const int* src = (const int*)d_in[1];
  const int* dst = (const int*)d_in[2];
  const float* l1w = (const float*)d_in[3];
  const float* l1b = (const float*)d_in[4];
  const float* gfc = (const float*)d_in[5];
  const float* al = (const float*)d_in[6];
  const float* ar = (const float*)d_in[7];
  const float* gbias = (const float*)d_in[8];
  const float* wih = (const float*)d_in[9];
  const float* whh = (const float*)d_in[10];
  const float* bih = (const float*)d_in[11];
  const float* bhh = (const float*)d_in[12];
  const float* l2w = (const float*)d_in[13];
  const float* l2b = (const float*)d_in[14];
  float* out = (float*)d_out;

  char* ws = (char*)d_ws;
  size_t o = 0;
  auto carve = [&](size_t bytes) -> char* {
    char* p = ws + o;
    o += (bytes + 255) & ~(size_t)255;
    return p;
  };
  float* x1 = (float*)carve((size_t)NN * HD * 4);
  float* hbuf = (float*)carve((size_t)NN * HD * 4);
  float* cbuf = (float*)carve((size_t)NN * HD * 4);
  float* feat = (float*)carve((size_t)NN * HD * 4);
  float* el = (float*)carve((size_t)NN * 4);
  float* er = (float*)carve((size_t)NN * 4);
  int* part = (int*)carve((size_t)NBK * NBUCKET * 4);
  int* totals = (int*)carve((size_t)NBUCKET * 4);
  int* segbase = (int*)carve((size_t)(NBUCKET + 1) * 4);
  int* off = (int*)carve((size_t)(NN + 1) * 4);
  int* binned = (int*)carve((size_t)NE * 4);
  int* csr = (int*)carve((size_t)NE * 4);

  // atomic-free counting-sort CSR build (graph static across layers)
  k_p0<<<NBK, 256, 0, stream>>>(dst, part);
  k_scan1<<<NBUCKET, 256, 0, stream>>>(part, totals);
  k_scan2<<<1, 256, 0, stream>>>(totals, segbase);
  k_p1<<<NBK, 256, 0, stream>>>(src, dst, part, segbase, binned);
  k_p2<<<NBUSED, 512, 0, stream>>>(binned, segbase, off, csr);

  k_lin1<<<2048, 256, 0, stream>>>(x, l1w, l1b, x1);

  const float* xin = x1;
  for (int l = 0; l < NL; ++l) {
    k_node<<<(NN + 255) / 256, 256, 0, stream>>>(
        xin, gfc + l * HD * HD, al + l * HD, ar + l * HD, feat, el, er);
    k_gat<<<(NN + 15) / 16, 256, 0, stream>>>(
        feat, el, er, off, csr, gbias + l * HD, wih + l * 4 * HD * HD,
        whh + l * 4 * HD * HD, bih + l * 4 * HD, bhh + l * 4 * HD, hbuf, cbuf,
        hbuf, cbuf, l2w, l2b, out, l == 0 ? 1 : 0, l == NL - 1 ? 1 : 0);
    xin = hbuf;
  }
}

// Round 11
// 405.219 us; speedup vs baseline: 1.1065x; 1.1065x over previous
//
#include <hip/hip_runtime.h>
#include <hip/hip_bf16.h>

// GeniePath forward: lin1 -> [GAT(edge softmax) + LSTM] x2 -> lin2
// R10: best-measured config (R7 k_gat, 417.9us total) + padded LDS
//      staging [HD][68]: keeps coalesced global reads (row=i>>4,j=i&15,
//      global idx == i) AND conflict-free LDS writes (68%32==4 -> bank
//      (4j+row)%32, exactly 2 lanes/bank = free) AND conflict-free LSTM
//      reads (16 consecutive addrs). R9's remap broke global coalescing
//      -- padding fixes both axes at once. Parallel scan kept.

#define NN 100000
#define NE 3200000
#define IND 256
#define HD 16
#define OD 64
#define NL 2
#define WPAD 68   // LDS pad: 68 % 32 == 4 -> 2-way (free) staging writes

#define NBK 512        // P0/P1 block count
#define CHUNK 6250     // NE / NBK, exact
#define NBUCKET 256    // coarse buckets (dst >> 9); 196 used
#define BSHIFT 9
#define NBUSED ((NN + 511) >> 9)  // 196

__device__ __forceinline__ float fsig(float x) {
  return 1.0f / (1.0f + __expf(-x));
}
// stable tanh: works for any magnitude (expf overflow -> +inf -> 2/inf = 0)
__device__ __forceinline__ float ftanh(float x) {
  float a = fabsf(x);
  float t = 1.0f - 2.0f / (__expf(2.0f * a) + 1.0f);
  return x < 0.0f ? -t : t;
}
__device__ __forceinline__ float leaky(float e) {
  return e > 0.0f ? e : 0.2f * e;
}

__device__ __forceinline__ int block_excl_scan(int v, int* lds) {
  const int lane = threadIdx.x & 63;
  const int w = threadIdx.x >> 6;
  const int nw = blockDim.x >> 6;
  int inc = v;
#pragma unroll
  for (int d = 1; d < 64; d <<= 1) {
    int u = __shfl_up(inc, d);
    if (lane >= d) inc += u;
  }
  if (lane == 63) lds[w] = inc;
  __syncthreads();
  int wbase = 0;
  for (int i = 0; i < nw; ++i) {
    int s = lds[i];
    if (i < w) wbase += s;
  }
  return wbase + inc - v;
}

// ---------------- lin1: y[N,16] = x[N,256] @ w[16,256]^T + b ----------------
__global__ __launch_bounds__(256) void k_lin1(const float* __restrict__ x,
                                              const float* __restrict__ w,
                                              const float* __restrict__ bias,
                                              float* __restrict__ y) {
  const int lane = threadIdx.x & 63;
  const int wid = (blockIdx.x * (blockDim.x >> 6)) + (threadIdx.x >> 6);
  const int nw = (gridDim.x * blockDim.x) >> 6;
  float4 wr[HD];
#pragma unroll
  for (int k = 0; k < HD; ++k)
    wr[k] = *reinterpret_cast<const float4*>(&w[k * IND + lane * 4]);
  // lane l (low 16) owns output k = bitrev4(l)
  const int krev = ((lane & 1) << 3) | ((lane & 2) << 1) | ((lane & 4) >> 1) | ((lane & 8) >> 3);
  const float bl = bias[krev];
  const int b0 = lane & 1, b1 = lane & 2, b2 = lane & 4, b3 = lane & 8;

  for (int n = wid; n < NN; n += nw) {
    float4 xv = *reinterpret_cast<const float4*>(&x[n * IND + lane * 4]);
    float acc[HD];
#pragma unroll
    for (int k = 0; k < HD; ++k)
      acc[k] = xv.x * wr[k].x + xv.y * wr[k].y + xv.z * wr[k].z + xv.w * wr[k].w;
    float v8[8];
#pragma unroll
    for (int j = 0; j < 8; ++j) {
      float send = b0 ? acc[j] : acc[j + 8];
      float recv = __shfl_xor(send, 1);
      v8[j] = (b0 ? acc[j + 8] : acc[j]) + recv;
    }
    float v4[4];
#pragma unroll
    for (int j = 0; j < 4; ++j) {
      float send = b1 ? v8[j] : v8[j + 4];
      float recv = __shfl_xor(send, 2);
      v4[j] = (b1 ? v8[j + 4] : v8[j]) + recv;
    }
    float v2[2];
#pragma unroll
    for (int j = 0; j < 2; ++j) {
      float send = b2 ? v4[j] : v4[j + 2];
      float recv = __shfl_xor(send, 4);
      v2[j] = (b2 ? v4[j + 2] : v4[j]) + recv;
    }
    float send = b3 ? v2[0] : v2[1];
    float recv = __shfl_xor(send, 8);
    float v1 = (b3 ? v2[1] : v2[0]) + recv;
    v1 += __shfl_xor(v1, 16);
    v1 += __shfl_xor(v1, 32);
    if (lane < HD) y[n * HD + krev] = v1 + bl;
  }
}

// ---------------- per-node GAT prologue: feat, el, er ----------------
__global__ __launch_bounds__(256) void k_node(const float* __restrict__ xin,
                                              const float* __restrict__ fc,
                                              const float* __restrict__ al,
                                              const float* __restrict__ ar,
                                              float* __restrict__ feat,
                                              float* __restrict__ el,
                                              float* __restrict__ er) {
  int n = blockIdx.x * blockDim.x + threadIdx.x;
  if (n >= NN) return;
  const float4* xp = reinterpret_cast<const float4*>(&xin[n * HD]);
  float xr[HD];
#pragma unroll
  for (int j = 0; j < 4; ++j) {
    float4 v = xp[j];
    xr[4 * j] = v.x; xr[4 * j + 1] = v.y; xr[4 * j + 2] = v.z; xr[4 * j + 3] = v.w;
  }
  float fr[HD];
  float e_l = 0.0f, e_r = 0.0f;
#pragma unroll
  for (int k = 0; k < HD; ++k) {
    float acc = 0.0f;
#pragma unroll
    for (int j = 0; j < HD; ++j) acc += xr[j] * fc[k * HD + j];
    fr[k] = acc;
    e_l += acc * al[k];
    e_r += acc * ar[k];
  }
  float4* fp = reinterpret_cast<float4*>(&feat[n * HD]);
  fp[0] = make_float4(fr[0], fr[1], fr[2], fr[3]);
  fp[1] = make_float4(fr[4], fr[5], fr[6], fr[7]);
  fp[2] = make_float4(fr[8], fr[9], fr[10], fr[11]);
  fp[3] = make_float4(fr[12], fr[13], fr[14], fr[15]);
  el[n] = e_l;
  er[n] = e_r;
}

// ---------------- build P0: per-block coarse histogram (no atomics) --------
__global__ __launch_bounds__(256) void k_p0(const int* __restrict__ dst,
                                            int* __restrict__ part) {
  __shared__ int hist[NBUCKET];
  for (int i = threadIdx.x; i < NBUCKET; i += 256) hist[i] = 0;
  __syncthreads();
  const int base = blockIdx.x * CHUNK;
  for (int i = threadIdx.x; i < CHUNK; i += 256)
    atomicAdd(&hist[dst[base + i] >> BSHIFT], 1);  // LDS atomic, cheap
  __syncthreads();
  for (int i = threadIdx.x; i < NBUCKET; i += 256)
    part[blockIdx.x * NBUCKET + i] = hist[i];
}

// ---------------- build scan (parallel): per-bucket block scan -------------
// one block per bucket b: scan part[0..511][b] in place, write totals[b]
__global__ __launch_bounds__(256) void k_scan1(int* __restrict__ part,
                                               int* __restrict__ totals) {
  __shared__ int lds[4];
  const int b = blockIdx.x;
  const int t = threadIdx.x;
  int v0 = part[(2 * t) * NBUCKET + b];
  int v1 = part[(2 * t + 1) * NBUCKET + b];
  int sum = v0 + v1;
  int ex = block_excl_scan(sum, lds);
  part[(2 * t) * NBUCKET + b] = ex;
  part[(2 * t + 1) * NBUCKET + b] = ex + v0;
  if (t == 255) totals[b] = ex + sum;
}

// exclusive scan of 256 bucket totals -> segbase
__global__ __launch_bounds__(256) void k_scan2(const int* __restrict__ totals,
                                               int* __restrict__ segbase) {
  __shared__ int lds[4];
  const int t = threadIdx.x;
  int v = totals[t];
  int ex = block_excl_scan(v, lds);
  segbase[t] = ex;
  if (t == NBUCKET - 1) segbase[NBUCKET] = ex + v;
}

// ---------------- build P1: bucket-grouped coalesced scatter ---------------
__global__ __launch_bounds__(256) void k_p1(const int* __restrict__ src,
                                            const int* __restrict__ dst,
                                            const int* __restrict__ part,
                                            const int* __restrict__ segbase,
                                            int* __restrict__ binned) {
  __shared__ int hist[NBUCKET];
  __shared__ int sc[NBUCKET];      // exclusive scan of hist (LDS layout)
  __shared__ int gb[NBUCKET];      // global base for this block's run per bucket
  __shared__ int cur[NBUCKET];
  __shared__ int stage[CHUNK];     // packed (src<<9 | dst&511), bucket-grouped
  __shared__ unsigned char bkt[CHUNK];
  __shared__ int lds4[4];
  for (int i = threadIdx.x; i < NBUCKET; i += 256) hist[i] = 0;
  __syncthreads();
  const int base = blockIdx.x * CHUNK;
  for (int i = threadIdx.x; i < CHUNK; i += 256)
    atomicAdd(&hist[dst[base + i] >> BSHIFT], 1);
  __syncthreads();
  {
    int v = hist[threadIdx.x];
    int ex = block_excl_scan(v, lds4);
    sc[threadIdx.x] = ex;
    cur[threadIdx.x] = 0;
    gb[threadIdx.x] = segbase[threadIdx.x] + part[blockIdx.x * NBUCKET + threadIdx.x];
  }
  __syncthreads();
  // stage bucket-grouped into LDS
  for (int i = threadIdx.x; i < CHUNK; i += 256) {
    int d = dst[base + i];
    int s = src[base + i];
    int b = d >> BSHIFT;
    int l = atomicAdd(&cur[b], 1);
    int slot = sc[b] + l;
    stage[slot] = (s << BSHIFT) | (d & ((1 << BSHIFT) - 1));
    bkt[slot] = (unsigned char)b;
  }
  __syncthreads();
  // stream out: consecutive slots -> same bucket mostly -> coalesced
  for (int i = threadIdx.x; i < CHUNK; i += 256) {
    int b = bkt[i];
    binned[gb[b] + (i - sc[b])] = stage[i];
  }
}

// ---------------- build P2: per-bucket fine CSR ----------------------------
__global__ __launch_bounds__(512) void k_p2(const int* __restrict__ binned,
                                            const int* __restrict__ segbase,
                                            int* __restrict__ off,
                                            int* __restrict__ csr) {
  const int b = blockIdx.x;  // 0..NBUSED-1
  const int lo = segbase[b];
  const int cnt = segbase[b + 1] - lo;
  __shared__ int hist[512], sc2[512], cur2[512];
  __shared__ int lds8[8];
  hist[threadIdx.x] = 0;
  __syncthreads();
  for (int i = threadIdx.x; i < cnt; i += 512)
    atomicAdd(&hist[binned[lo + i] & 511], 1);
  __syncthreads();
  int v = hist[threadIdx.x];
  int ex = block_excl_scan(v, lds8);
  sc2[threadIdx.x] = ex;
  cur2[threadIdx.x] = 0;
  int node = (b << BSHIFT) + threadIdx.x;
  if (node < NN) off[node] = lo + ex;
  if (b == 0 && threadIdx.x == 0) off[NN] = NE;
  __syncthreads();
  for (int i = threadIdx.x; i < cnt; i += 512) {
    int w = binned[lo + i];
    int ld = w & 511;
    int l = atomicAdd(&cur2[ld], 1);          // LDS atomic
    csr[lo + sc2[ld] + l] = w >> BSHIFT;      // write within L2-resident window
  }
}

// ---------------- fused GAT aggregate + LSTM cell (+ lin2 on last layer) ----
// block = 256 thr = 4 waves; wave = 4 nodes x 16 lanes.
// Edge loop (R7, best measured): lane q owns edge t0+q end-to-end.
// acc[] indexed by bitrev4(dim); value-halving butterfly lands dim p on
// lane p. Staging: coalesced global (idx==i) + WPAD=68 LDS pad -> 2-way
// (free) write banks, conflict-free LSTM reads.
__global__ __launch_bounds__(256) void k_gat(const float* __restrict__ feat,
                                             const float* __restrict__ el,
                                             const float* __restrict__ er,
                                             const int* __restrict__ off,
                                             const int* __restrict__ csr_src,
                                             const float* __restrict__ gbias,
                                             const float* __restrict__ wih,
                                             const float* __restrict__ whh,
                                             const float* __restrict__ bih,
                                             const float* __restrict__ bhh,
                                             const float* __restrict__ h_in,
                                             const float* __restrict__ c_in,
                                             float* __restrict__ h_out,
                                             float* __restrict__ c_out,
                                             const float* __restrict__ w2,
                                             const float* __restrict__ b2,
                                             float* __restrict__ out,
                                             int first, int last) {
  __shared__ float s_wih[HD][WPAD];  // [j][gate*16+p], padded
  __shared__ float s_whh[HD][WPAD];
  __shared__ float s_b[64];
  __shared__ float s_gb[HD];
  __shared__ float s_w2[HD][WPAD];   // [j][o], padded
  __shared__ float s_b2[OD];
  for (int i = threadIdx.x; i < 64 * HD; i += blockDim.x) {
    int row = i >> 4;   // global idx row*HD+j == i -> coalesced reads
    int j = i & 15;
    s_wih[j][row] = wih[row * HD + j];
    s_whh[j][row] = whh[row * HD + j];
    s_w2[j][row] = w2[row * HD + j];  // 64 rows x 16 cols, same shape
  }
  if (threadIdx.x < 64) {
    s_b[threadIdx.x] = bih[threadIdx.x] + bhh[threadIdx.x];
    s_b2[threadIdx.x] = b2[threadIdx.x];
  }
  if (threadIdx.x < HD) s_gb[threadIdx.x] = gbias[threadIdx.x];
  __syncthreads();

  const int lane = threadIdx.x & 63;
  const int p = lane & 15;
  const int lb = lane & 48;  // group base lane
  const int grp = lane >> 4;
  const int wave = threadIdx.x >> 6;
  int n = blockIdx.x * 16 + wave * 4 + grp;
  bool valid = n < NN;
  int base = 0, deg = 0;
  float ern = 0.0f;
  if (valid) {
    base = off[n];
    deg = off[n + 1] - base;
    ern = er[n];
  }
  const int b0 = lane & 1, b1 = lane & 2, b2_ = lane & 4, b3 = lane & 8;

  // softmax without max subtraction (scale-invariant; logits O(5) by
  // construction). Lane q of the group owns edges t0+q: private ex,
  // private acc[16] over its edges' feat rows. acc[bitrev4(k)] = dim k.
  float ssum = 0.0f;
  float acc[HD];
#pragma unroll
  for (int k = 0; k < HD; ++k) acc[k] = 0.0f;
  for (int t0 = 0; t0 < deg; t0 += 16) {
    int t = t0 + p;
    bool ok = t < deg;
    int tc = ok ? t : (deg - 1);        // clamped: loads always safe
    int s = csr_src[base + tc];         // coalesced 64B per group
    float ex = ok ? __expf(leaky(el[s] + ern)) : 0.0f;
    ssum += ex;
    const float4* fp4 = reinterpret_cast<const float4*>(&feat[s * HD]);
    float4 f0 = fp4[0], f1 = fp4[1], f2 = fp4[2], f3 = fp4[3];
    // dim k -> acc[bitrev4(k)]
    acc[0]  += ex * f0.x;  // k=0
    acc[8]  += ex * f0.y;  // k=1
    acc[4]  += ex * f0.z;  // k=2
    acc[12] += ex * f0.w;  // k=3
    acc[2]  += ex * f1.x;  // k=4
    acc[10] += ex * f1.y;  // k=5
    acc[6]  += ex * f1.z;  // k=6
    acc[14] += ex * f1.w;  // k=7
    acc[1]  += ex * f2.x;  // k=8
    acc[9]  += ex * f2.y;  // k=9
    acc[5]  += ex * f2.z;  // k=10
    acc[13] += ex * f2.w;  // k=11
    acc[3]  += ex * f3.x;  // k=12
    acc[11] += ex * f3.y;  // k=13
    acc[7]  += ex * f3.z;  // k=14
    acc[15] += ex * f3.w;  // k=15
  }
  // ssum: all-reduce within the 16-lane group (4 shuffles)
  ssum += __shfl_xor(ssum, 1);
  ssum += __shfl_xor(ssum, 2);
  ssum += __shfl_xor(ssum, 4);
  ssum += __shfl_xor(ssum, 8);
  // value-halving butterfly: lane l ends with acc[bitrev4(l)] = dim l total
  float v8[8];
#pragma unroll
  for (int j = 0; j < 8; ++j) {
    float send = b0 ? acc[j] : acc[j + 8];
    float recv = __shfl_xor(send, 1);
    v8[j] = (b0 ? acc[j + 8] : acc[j]) + recv;
  }
  float v4[4];
#pragma unroll
  for (int j = 0; j < 4; ++j) {
    float send = b1 ? v8[j] : v8[j + 4];
    float recv = __shfl_xor(send, 2);
    v4[j] = (b1 ? v8[j + 4] : v8[j]) + recv;
  }
  float v2[2];
#pragma unroll
  for (int j = 0; j < 2; ++j) {
    float send = b2_ ? v4[j] : v4[j + 2];
    float recv = __shfl_xor(send, 4);
    v2[j] = (b2_ ? v4[j + 2] : v4[j]) + recv;
  }
  float send1 = b3 ? v2[0] : v2[1];
  float recv1 = __shfl_xor(send1, 8);
  float a = (b3 ? v2[1] : v2[0]) + recv1;

  float inv = (deg > 0) ? 1.0f / ssum : 0.0f;
  float g_in = ftanh(a * inv + s_gb[p]);

  // LSTM cell (dim p of node n)
  float h_old = 0.0f, c_old = 0.0f;
  if (!first && valid) {
    h_old = h_in[n * HD + p];
    c_old = c_in[n * HD + p];
  }
  float g0 = 0.0f, g1 = 0.0f, g2 = 0.0f, g3 = 0.0f;
#pragma unroll
  for (int j = 0; j < HD; ++j) {
    float gj = __shfl(g_in, lb + j);
    float hj = __shfl(h_old, lb + j);
    g0 += gj * s_wih[j][p] + hj * s_whh[j][p];
    g1 += gj * s_wih[j][16 + p] + hj * s_whh[j][16 + p];
    g2 += gj * s_wih[j][32 + p] + hj * s_whh[j][32 + p];
    g3 += gj * s_wih[j][48 + p] + hj * s_whh[j][48 + p];
  }
  g0 += s_b[p]; g1 += s_b[16 + p]; g2 += s_b[32 + p]; g3 += s_b[48 + p];
  float ig = fsig(g0), fg = fsig(g1), gg = ftanh(g2), og = fsig(g3);
  float c_new = fg * c_old + ig * gg;
  float h_new = og * ftanh(c_new);

  if (valid) {
    if (!last) {
      h_out[n * HD + p] = h_new;
      c_out[n * HD + p] = c_new;
    } else {
      // fused lin2: out[n,o] = sum_j h[j] * w2[o][j] + b2[o]
      float o0 = s_b2[p], o1 = s_b2[16 + p], o2 = s_b2[32 + p], o3 = s_b2[48 + p];
#pragma unroll
      for (int j = 0; j < HD; ++j) {
        float hj = __shfl(h_new, lb + j);
        o0 += hj * s_w2[j][p];
        o1 += hj * s_w2[j][16 + p];
        o2 += hj * s_w2[j][32 + p];
        o3 += hj * s_w2[j][48 + p];
      }
      out[n * OD + p] = o0;
      out[n * OD + 16 + p] = o1;
      out[n * OD + 32 + p] = o2;
      out[n * OD + 48 + p] = o3;
    }
  }
}

extern "C" void kernel_launch(void* const* d_in, const int* in_sizes, int n_in,
                              void* d_out, int out_size, void* d_ws, size_t ws_size,
                              hipStream_t stream) {
  const float* x = (const float*)d_in[0];
  const int* src = (const int*)d_in[1];
  const int* dst = (const int*)d_in[2];
  const float* l1w = (const float*)d_in[3];
  const float* l1b = (const float*)d_in[4];
  const float* gfc = (const float*)d_in[5];
  const float* al = (const float*)d_in[6];
  const float* ar = (const float*)d_in[7];
  const float* gbias = (const float*)d_in[8];
  const float* wih = (const float*)d_in[9];
  const float* whh = (const float*)d_in[10];
  const float* bih = (const float*)d_in[11];
  const float* bhh = (const float*)d_in[12];
  const float* l2w = (const float*)d_in[13];
  const float* l2b = (const float*)d_in[14];
  float* out = (float*)d_out;

  char* ws = (char*)d_ws;
  size_t o = 0;
  auto carve = [&](size_t bytes) -> char* {
    char* p = ws + o;
    o += (bytes + 255) & ~(size_t)255;
    return p;
  };
  float* x1 = (float*)carve((size_t)NN * HD * 4);
  float* hbuf = (float*)carve((size_t)NN * HD * 4);
  float* cbuf = (float*)carve((size_t)NN * HD * 4);
  float* feat = (float*)carve((size_t)NN * HD * 4);
  float* el = (float*)carve((size_t)NN * 4);
  float* er = (float*)carve((size_t)NN * 4);
  int* part = (int*)carve((size_t)NBK * NBUCKET * 4);
  int* totals = (int*)carve((size_t)NBUCKET * 4);
  int* segbase = (int*)carve((size_t)(NBUCKET + 1) * 4);
  int* off = (int*)carve((size_t)(NN + 1) * 4);
  int* binned = (int*)carve((size_t)NE * 4);
  int* csr = (int*)carve((size_t)NE * 4);

  // atomic-free counting-sort CSR build (graph static across layers)
  k_p0<<<NBK, 256, 0, stream>>>(dst, part);
  k_scan1<<<NBUCKET, 256, 0, stream>>>(part, totals);
  k_scan2<<<1, 256, 0, stream>>>(totals, segbase);
  k_p1<<<NBK, 256, 0, stream>>>(src, dst, part, segbase, binned);
  k_p2<<<NBUSED, 512, 0, stream>>>(binned, segbase, off, csr);

  k_lin1<<<2048, 256, 0, stream>>>(x, l1w, l1b, x1);

  const float* xin = x1;
  for (int l = 0; l < NL; ++l) {
    k_node<<<(NN + 255) / 256, 256, 0, stream>>>(
        xin, gfc + l * HD * HD, al + l * HD, ar + l * HD, feat, el, er);
    k_gat<<<(NN + 15) / 16, 256, 0, stream>>>(
        feat, el, er, off, csr, gbias + l * HD, wih + l * 4 * HD * HD,
        whh + l * 4 * HD * HD, bih + l * 4 * HD, bhh + l * 4 * HD, hbuf, cbuf,
        hbuf, cbuf, l2w, l2b, out, l == 0 ? 1 : 0, l == NL - 1 ? 1 : 0);
    xin = hbuf;
  }
}